// Round 1
// baseline (1159.714 us; speedup 1.0000x reference)
//
#include <hip/hip_runtime.h>

// ---------------------------------------------------------------------------
// Problem constants
// ---------------------------------------------------------------------------
constexpr int CT = 32;      // T
constexpr int CN = 64;      // N
constexpr int CE = 256;     // E = DOBS*V
constexpr int CHID = 1024;
constexpr int CA = 32;      // num options
constexpr int CS = 32;      // planning steps
constexpr int CHP = 8;      // planning horizon
constexpr int TN = CT * CN; // 2048

// d_out float offsets (return order: search_logits, planned_actions, X, value,
// model_loss, embed_loss)
constexpr size_t O_SL  = 0;        // 32*64*32 = 65536
constexpr size_t O_PA  = 65536;    // 64*8     = 512
constexpr size_t O_X   = 66048;    // 64*8*256 = 131072
constexpr size_t O_VAL = 197120;   // 32*64    = 2048
constexpr size_t O_ML  = 199168;   // 32*64*256= 524288
constexpr size_t O_EL  = 723456;   // 32*64    = 2048

// ws byte offsets (needs ~100 MB)
constexpr size_t B_EMB    = 0;                         // 2 MB   [2048][256] f32
constexpr size_t B_H1     = 2u * 1024 * 1024;          // 256 KB [64][1024]
constexpr size_t B_XS     = B_H1 + 256 * 1024;         // 128 KB [64][512]
constexpr size_t B_HBUF   = B_XS + 128 * 1024;         // 256 KB [64][1024]
constexpr size_t B_PART   = B_HBUF + 256 * 1024;       // 1 MB   [64][16][256]
constexpr size_t B_LOG    = B_PART + 1024 * 1024;      // 8 KB   [64][32]
constexpr size_t B_IBUF   = B_LOG + 8 * 1024;
constexpr size_t B_IUP    = B_IBUF + 1024;
constexpr size_t B_PUSH   = B_IUP + 1024;
constexpr size_t B_CNT    = B_PUSH + 1024;
constexpr size_t B_LISTP  = B_CNT + 1024;              // 8 KB [32][64]
constexpr size_t B_CNTTL  = B_LISTP + 8 * 1024;
constexpr size_t B_LISTTL = B_CNTTL + 1024;            // 32 KB [32][256]
// 32MB multi-phase region: We2T (early) -> Wm1T (mid) -> xs_tl/hbig/part_tl/Wm2T
constexpr size_t B_R32    = 4u * 1024 * 1024;
constexpr size_t B_WE2T   = B_R32;                     // 1 MB  (phase 1, dead after x0)
constexpr size_t B_WM1T   = B_R32;                     // 32 MB (phase 2, dead after wpm)
constexpr size_t B_XSTL   = B_R32;                     // 4 MB  [2048][512]   (phase 3)
constexpr size_t B_HBIG   = B_R32 + 4u * 1024 * 1024;  // 8 MB  [2048][1024]
constexpr size_t B_PARTTL = B_R32 + 12u * 1024 * 1024; // 8 MB  [2048][4][256]
constexpr size_t B_WM2T   = B_R32 + 28u * 1024 * 1024; // 1 MB  [1024][256]
constexpr size_t B_WPM    = B_R32 + 32u * 1024 * 1024; // 64 MB [32][512][1024]

__device__ __forceinline__ void fma4(float4& a, float s, const float4& w) {
  a.x += s * w.x; a.y += s * w.y; a.z += s * w.z; a.w += s * w.w;
}

// ---------------------------------------------------------------------------
// init: zero PA+X span of d_out, logits state, option counters
// ---------------------------------------------------------------------------
__global__ void init_kernel(float* __restrict__ out, float* __restrict__ logits,
                            int* __restrict__ cnt, int* __restrict__ cnt_tl) {
  int idx = blockIdx.x * 256 + threadIdx.x;
  if (idx < 131584) out[O_PA + idx] = 0.f;  // PA (512) + X (131072) contiguous
  if (idx < CN * CA) logits[idx] = 0.f;
  if (idx < CA) { cnt[idx] = 0; cnt_tl[idx] = 0; }
}

// ---------------------------------------------------------------------------
// emb[t][n][e] = embed1[obs[t][n][e>>4]][e&15]
// ---------------------------------------------------------------------------
__global__ void emb_kernel(const int* __restrict__ obs, const float* __restrict__ embed1,
                           float* __restrict__ emb) {
  int idx = blockIdx.x * 256 + threadIdx.x;   // 65536 threads: (b, group of 8 e)
  int b = idx >> 5, k8 = idx & 31;
  int e0 = k8 * 8;
  int d = e0 >> 4;
  int o = obs[b * 16 + d];
  const float* src = embed1 + o * 16 + (e0 & 15);
  float4 v0 = *(const float4*)src;
  float4 v1 = *(const float4*)(src + 4);
  float* dst = emb + (size_t)b * CE + e0;
  *(float4*)dst = v0;
  *(float4*)(dst + 4) = v1;
}

// ---------------------------------------------------------------------------
// One GRU step with h0 = 0 (only Hs[0] is ever used downstream):
// h1 = (1-z)*tanh(inn + r*bhh_n),  r/z from (x@Wih.T + bih + bhh)
// ---------------------------------------------------------------------------
__global__ void h1_kernel(const float* __restrict__ emb, const float* __restrict__ Wih,
                          const float* __restrict__ bih, const float* __restrict__ bhh,
                          float* __restrict__ h1) {
  int t = threadIdx.x, bid = blockIdx.x;   // 256 blocks of (64n x 4j)
  int n = t & 63, j = bid * 4 + (t >> 6);
  const float* x = emb + (size_t)n * CE;   // emb[0] rows
  const float* wr = Wih + (size_t)j * CE;
  const float* wz = Wih + (size_t)(CHID + j) * CE;
  const float* wn = Wih + (size_t)(2 * CHID + j) * CE;
  float ar = 0.f, az = 0.f, an = 0.f;
  #pragma unroll 4
  for (int e = 0; e < CE; ++e) {
    float xe = x[e];
    ar += xe * wr[e]; az += xe * wz[e]; an += xe * wn[e];
  }
  ar += bih[j] + bhh[j];
  az += bih[CHID + j] + bhh[CHID + j];
  float r = 1.f / (1.f + expf(-ar));
  float z = 1.f / (1.f + expf(-az));
  float nn = tanhf(an + bih[2 * CHID + j] + r * bhh[2 * CHID + j]);
  h1[(size_t)n * CHID + j] = (1.f - z) * nn;
}

// ---------------------------------------------------------------------------
// Generic 64x64 tiled transpose: in[R][C] -> out[C][R]
// ---------------------------------------------------------------------------
__global__ void trans_kernel(const float* __restrict__ in, float* __restrict__ out,
                             int R, int C) {
  __shared__ float tile[64][65];
  int tj = threadIdx.x & 63, tg = threadIdx.x >> 6;
  int cb = blockIdx.x * 64, rb = blockIdx.y * 64;
  #pragma unroll
  for (int i = 0; i < 16; ++i) {
    int r = tg * 16 + i;
    tile[r][tj] = in[(size_t)(rb + r) * C + cb + tj];
  }
  __syncthreads();
  #pragma unroll
  for (int i = 0; i < 16; ++i) {
    int c2 = tg * 16 + i;
    out[(size_t)(cb + c2) * R + rb + tj] = tile[tj][c2];
  }
}

// ---------------------------------------------------------------------------
// X[:,0] = h1 @ We2^T + be2   (We2T layout [k][e])
// grid (4 e-tiles, 64 n), 256 thr = (64 e-lanes x 4 k-quarters)
// ---------------------------------------------------------------------------
__global__ void x0_kernel(const float* __restrict__ h1, const float* __restrict__ We2T,
                          const float* __restrict__ be2, float* __restrict__ Xout) {
  int et = blockIdx.x, n = blockIdx.y, t = threadIdx.x;
  int el = t & 63, kq = t >> 6;
  __shared__ float hr[1024];
  __shared__ float sred2[4][64];
  for (int idx = t; idx < 1024; idx += 256) hr[idx] = h1[(size_t)n * CHID + idx];
  __syncthreads();
  int e = et * 64 + el;
  float acc = 0.f;
  for (int k = kq * 256; k < kq * 256 + 256; ++k) acc += hr[k] * We2T[(size_t)k * CE + e];
  sred2[kq][el] = acc;
  __syncthreads();
  if (t < 64) {
    float s2 = sred2[0][t] + sred2[1][t] + sred2[2][t] + sred2[3][t] + be2[et * 64 + t];
    Xout[(size_t)(n * CHP) * CE + et * 64 + t] = s2;
  }
}

// ---------------------------------------------------------------------------
// Factorized model weights:
// Wpm[o][e][j]     = sum_a relu( embed_opt[o][a]) * Wm1[j][a*256+e]
// Wpm[o][256+e][j] = sum_a relu(-embed_opt[o][a]) * Wm1[j][a*256+e]
// consumes Wm1T [8192][1024]; grid (256 e, 4 j-tiles), 256 thr
// ---------------------------------------------------------------------------
__global__ void wpm_kernel(const float* __restrict__ Wm1T, const float* __restrict__ eo,
                           float* __restrict__ Wpm) {
  int e = blockIdx.x, jt = blockIdx.y, t = threadIdx.x;
  int j = jt * 256 + t;
  __shared__ float rp[CA * CA], rm[CA * CA];
  for (int idx = t; idx < CA * CA; idx += 256) {
    float v = eo[idx];
    rp[idx] = fmaxf(v, 0.f);
    rm[idx] = fmaxf(-v, 0.f);
  }
  __syncthreads();
  float w[32];
  #pragma unroll
  for (int a = 0; a < 32; ++a) w[a] = Wm1T[(size_t)(a * 256 + e) * CHID + j];
  for (int o = 0; o < 32; ++o) {
    float sp = 0.f, sm = 0.f;
    #pragma unroll
    for (int a = 0; a < 32; ++a) {
      float wa = w[a];
      sp += rp[o * 32 + a] * wa;
      sm += rm[o * 32 + a] * wa;
    }
    Wpm[((size_t)o * 512 + e) * CHID + j] = sp;
    Wpm[((size_t)o * 512 + 256 + e) * CHID + j] = sm;
  }
}

// ---------------------------------------------------------------------------
// Group time-loop rows by option (list order nondeterministic; results aren't)
// ---------------------------------------------------------------------------
__global__ void tllists_kernel(const int* __restrict__ P, int* __restrict__ cnt_tl,
                               int* __restrict__ list_tl) {
  int b = blockIdx.x * 256 + threadIdx.x;
  if (b >= TN) return;
  int a = P[b];
  int slot = atomicAdd(&cnt_tl[a], 1);
  list_tl[a * 256 + slot] = b;
}

// xs_tl[b][k] = relu(+/- prev[b][k&255]),  prev = emb shifted by one t (wrap)
__global__ void xstl_kernel(const float* __restrict__ emb, float* __restrict__ xs) {
  int idx = blockIdx.x * 256 + threadIdx.x;   // < 2048*512
  int b = idx >> 9, k = idx & 511;
  int e = k & 255;
  int bp = (b < CN) ? (b + (CT - 1) * CN) : (b - CN);
  float v = emb[(size_t)bp * CE + e];
  xs[idx] = (k < 256) ? fmaxf(v, 0.f) : fmaxf(-v, 0.f);
}

// ---------------------------------------------------------------------------
// Factorized model layer 1 (shared by time loop and planning loop):
// h[row][j] = relu( sum_{k<512} xs[row][k] * Wpm[o][k][j] + bm1[j] )
// grid (32 o, 8 j-tiles of 128, Z row-group start); per group: 8 rows
// ---------------------------------------------------------------------------
__global__ __launch_bounds__(256) void l1_kernel(
    const float* __restrict__ Wpm, const float* __restrict__ xs,
    const float* __restrict__ bm1, const int* __restrict__ cnt,
    const int* __restrict__ list, int listStride, float* __restrict__ hout) {
  int o = blockIdx.x, jt = blockIdx.y;
  int c = cnt[o];
  if (c <= 0) return;
  __shared__ __align__(16) float sbuf[8192];  // xs stage (4096) then kq-partials (8192)
  __shared__ int srows[8];
  int t = threadIdx.x;
  int jl = t & 31, kq = t >> 5;
  int jb = jt * 128;
  const float* wb = Wpm + (size_t)o * (512 * CHID) + jb + jl * 4;
  for (int g = blockIdx.z; g * 8 < c; g += gridDim.z) {
    int base = g * 8;
    int nr = min(8, c - base);
    if (t < 8) srows[t] = (t < nr) ? list[o * listStride + base + t] : -1;
    __syncthreads();
    for (int idx = t; idx < 4096; idx += 256) {
      int row = srows[idx >> 9];
      sbuf[idx] = (row >= 0) ? xs[(size_t)row * 512 + (idx & 511)] : 0.f;
    }
    __syncthreads();
    float4 acc[8];
    #pragma unroll
    for (int r = 0; r < 8; ++r) acc[r] = make_float4(0.f, 0.f, 0.f, 0.f);
    int kbase = kq * 64;
    for (int k4 = 0; k4 < 64; k4 += 4) {
      int k = kbase + k4;
      float4 w0 = *(const float4*)(wb + (size_t)(k + 0) * CHID);
      float4 w1 = *(const float4*)(wb + (size_t)(k + 1) * CHID);
      float4 w2 = *(const float4*)(wb + (size_t)(k + 2) * CHID);
      float4 w3 = *(const float4*)(wb + (size_t)(k + 3) * CHID);
      #pragma unroll
      for (int r = 0; r < 8; ++r) {
        float4 xv = *(const float4*)&sbuf[r * 512 + k];
        fma4(acc[r], xv.x, w0); fma4(acc[r], xv.y, w1);
        fma4(acc[r], xv.z, w2); fma4(acc[r], xv.w, w3);
      }
    }
    __syncthreads();
    #pragma unroll
    for (int r = 0; r < 8; ++r)
      *(float4*)&sbuf[(kq * 8 + r) * 128 + jl * 4] = acc[r];
    __syncthreads();
    for (int idx = t; idx < 1024; idx += 256) {
      int r = idx >> 7, jc = idx & 127;
      float s = 0.f;
      #pragma unroll
      for (int q = 0; q < 8; ++q) s += sbuf[(q * 8 + r) * 128 + jc];
      int row = srows[r];
      if (row >= 0)
        hout[(size_t)row * CHID + jb + jc] = fmaxf(s + bm1[jb + jc], 0.f);
    }
    __syncthreads();
  }
}

// ---------------------------------------------------------------------------
// Time-loop layer 2 partials: part[b][kq][e] = sum_{k in kq*256..} h[b][k]*Wm2T[k][e]
// grid (4 kq, 64 row-groups of 32), 256 thr (= e)
// ---------------------------------------------------------------------------
__global__ __launch_bounds__(256) void l2big_kernel(const float* __restrict__ h,
    const float* __restrict__ Wm2T, float* __restrict__ part) {
  int kq = blockIdx.x, rg = blockIdx.y, t = threadIdx.x;
  int rb = rg * 32, kb = kq * 256;
  __shared__ __align__(16) float hl[8192];
  for (int idx = t; idx < 8192; idx += 256)
    hl[idx] = h[(size_t)(rb + (idx >> 8)) * CHID + kb + (idx & 255)];
  __syncthreads();
  float acc[32];
  #pragma unroll
  for (int r = 0; r < 32; ++r) acc[r] = 0.f;
  for (int kk = 0; kk < 256; kk += 4) {
    float w0 = Wm2T[(size_t)(kb + kk + 0) * CE + t];
    float w1 = Wm2T[(size_t)(kb + kk + 1) * CE + t];
    float w2 = Wm2T[(size_t)(kb + kk + 2) * CE + t];
    float w3 = Wm2T[(size_t)(kb + kk + 3) * CE + t];
    #pragma unroll
    for (int r = 0; r < 32; ++r) {
      float4 hv = *(const float4*)&hl[r * 256 + kk];
      acc[r] += hv.x * w0 + hv.y * w1 + hv.z * w2 + hv.w * w3;
    }
  }
  #pragma unroll
  for (int r = 0; r < 32; ++r)
    part[((size_t)(rb + r) * 4 + kq) * CE + t] = acc[r];
}

// model_loss = (sum(partials)+bm2 - emb)^2
__global__ void ml_kernel(const float* __restrict__ part, const float* __restrict__ bm2,
                          const float* __restrict__ emb, float* __restrict__ ML) {
  int idx = blockIdx.x * 256 + threadIdx.x;   // < 2048*256
  int b = idx >> 8, e = idx & 255;
  float outv = bm2[e];
  #pragma unroll
  for (int q = 0; q < 4; ++q) outv += part[((size_t)b * 4 + q) * CE + e];
  float d = outv - emb[idx];
  ML[idx] = d * d;
}

// ---------------------------------------------------------------------------
// Planning layer 2 partials: part[n][kq][e], kq<16 slices of 64 k
// grid (16 kq, 4 n-groups of 16), 256 thr.  Also zeroes plan cnt for next fin.
// ---------------------------------------------------------------------------
__global__ __launch_bounds__(256) void pl2_kernel(const float* __restrict__ h,
    const float* __restrict__ Wm2T, float* __restrict__ part, int* __restrict__ cnt) {
  int kq = blockIdx.x, ng = blockIdx.y, t = threadIdx.x;
  if (kq == 0 && ng == 0 && t < CA) cnt[t] = 0;
  int nb = ng * 16, kb = kq * 64;
  __shared__ __align__(16) float hl[1024];
  for (int idx = t; idx < 1024; idx += 256)
    hl[idx] = h[(size_t)(nb + (idx >> 6)) * CHID + kb + (idx & 63)];
  __syncthreads();
  float acc[16];
  #pragma unroll
  for (int r = 0; r < 16; ++r) acc[r] = 0.f;
  for (int kk = 0; kk < 64; kk += 4) {
    float w0 = Wm2T[(size_t)(kb + kk + 0) * CE + t];
    float w1 = Wm2T[(size_t)(kb + kk + 1) * CE + t];
    float w2 = Wm2T[(size_t)(kb + kk + 2) * CE + t];
    float w3 = Wm2T[(size_t)(kb + kk + 3) * CE + t];
    #pragma unroll
    for (int r = 0; r < 16; ++r) {
      float4 hv = *(const float4*)&hl[r * 64 + kk];
      acc[r] += hv.x * w0 + hv.y * w1 + hv.z * w2 + hv.w * w3;
    }
  }
  #pragma unroll
  for (int r = 0; r < 16; ++r)
    part[((size_t)(nb + r) * 16 + kq) * CE + t] = acc[r];
}

// ---------------------------------------------------------------------------
// fin(s): epilogue of step s-1 (reduce partials -> x_next, X/I update) + full
// decision phase of step s (gather x, sharp, vals, sl/logits/value/pa, push,
// xs for the model). s==32: epilogue only. 64 blocks (one per n), 256 thr.
// ---------------------------------------------------------------------------
__global__ __launch_bounds__(256) void fin_kernel(int s,
    const int* __restrict__ P, const float* __restrict__ Ws, const float* __restrict__ bsp,
    const float* __restrict__ Wc, const float* __restrict__ bc, const float* __restrict__ bm2,
    const float* __restrict__ part, float* __restrict__ Xout, float* __restrict__ SLout,
    float* __restrict__ VALout, float* __restrict__ PAout, float* __restrict__ logits,
    int* __restrict__ Ibuf, int* __restrict__ Iupbuf, int* __restrict__ pushbuf,
    float* __restrict__ xsbuf, int* __restrict__ cnt, int* __restrict__ listp) {
  int n = blockIdx.x, t = threadIdx.x;
  __shared__ float sx[256], sred[256], svals[32];
  __shared__ float ssharp;
  __shared__ int sflag, sI;
  if (s > 0) {
    int push = pushbuf[n];
    int I = Ibuf[n], Iup = Iupbuf[n];
    if (push) {
      float outv = bm2[t];
      #pragma unroll
      for (int q = 0; q < 16; ++q) outv += part[((size_t)n * 16 + q) * CE + t];
      Xout[((size_t)(n * CHP) + Iup) * CE + t] = outv;
      sx[t] = outv;
      if (t == 0) sI = Iup;
    } else {
      int Inew = (I - 1 > 0) ? I - 1 : 0;
      sx[t] = Xout[((size_t)(n * CHP) + Inew) * CE + t];
      if (t == 0) sI = Inew;
    }
    if (s == CS) return;  // final epilogue only
  } else {
    sx[t] = Xout[((size_t)(n * CHP)) * CE + t];
    if (t == 0) sI = 0;
  }
  __syncthreads();
  int I = sI;
  if (t == 0) Ibuf[n] = I;
  float xv = sx[t];
  float xa = fmaxf(xv, 0.f);
  xsbuf[n * 512 + t] = xa;
  xsbuf[n * 512 + 256 + t] = fmaxf(-xv, 0.f);
  sred[t] = xa * Ws[t];
  __syncthreads();
  #pragma unroll
  for (int off = 128; off > 0; off >>= 1) {
    if (t < off) sred[t] += sred[t + off];
    __syncthreads();
  }
  if (t == 0) { ssharp = sred[0] + bsp[0]; sflag = 1; }
  int c = t >> 3, g = t & 7;
  float pv = 0.f;
  #pragma unroll 4
  for (int i = 0; i < 32; ++i) {
    int e = g * 32 + i;
    pv += fmaxf(sx[e], 0.f) * Wc[c * CE + e];
  }
  pv += __shfl_down(pv, 4, 8);
  pv += __shfl_down(pv, 2, 8);
  pv += __shfl_down(pv, 1, 8);
  if (g == 0) svals[c] = pv + bc[c];
  __syncthreads();
  if (t < CA && logits[n * CA + t] != 0.f) sflag = 0;
  __syncthreads();
  int a = P[s * CN + n];
  if (t < CA) {
    float v = svals[t];
    float slv = sflag ? ssharp * v : logits[n * CA + t];
    SLout[(size_t)(s * CN + n) * CA + t] = slv;
    logits[n * CA + t] = slv - (t == a ? 1e8f : 0.f);
    if (t == a) {
      VALout[s * CN + n] = slv;
      int pn = (v > 0.f) ? 1 : 0;
      pushbuf[n] = pn;
      PAout[n * CHP + I] = (float)a;
      Iupbuf[n] = (I + 1 < CHP - 1) ? I + 1 : CHP - 1;
      if (pn) {
        int slot = atomicAdd(&cnt[a], 1);
        listp[a * CN + slot] = n;
      }
    }
  }
}

// ---------------------------------------------------------------------------
// embed_loss: cos(emb_n, X_n), logp = log_softmax(sharp*cos over HP), sum p*logp
// one block per (t,n); 256 thr = (8 h x 32 lanes)
// ---------------------------------------------------------------------------
__global__ void el_kernel(const float* __restrict__ emb, const float* __restrict__ Xout,
                          const float* __restrict__ Ws, const float* __restrict__ bsp,
                          float* __restrict__ EL) {
  int tn = blockIdx.x;
  int n = tn & 63;
  int t = threadIdx.x, h = t >> 5, l = t & 31;
  const float* er = emb + (size_t)tn * CE;
  const float* xr = Xout + ((size_t)(n * CHP) + h) * CE;
  float pd = 0.f, px = 0.f, pe = 0.f, ps = 0.f;
  #pragma unroll
  for (int i = 0; i < 8; ++i) {
    int e = l * 8 + i;
    float ev = er[e], xv2 = xr[e];
    pd += ev * xv2; px += xv2 * xv2; pe += ev * ev; ps += fmaxf(ev, 0.f) * Ws[e];
  }
  #pragma unroll
  for (int off = 16; off > 0; off >>= 1) {
    pd += __shfl_down(pd, off, 32);
    px += __shfl_down(px, off, 32);
    pe += __shfl_down(pe, off, 32);
    ps += __shfl_down(ps, off, 32);
  }
  __shared__ float sdot[8], snx[8];
  __shared__ float sne, ssh;
  if (l == 0) {
    sdot[h] = pd;
    snx[h] = sqrtf(px);
    if (h == 0) { sne = sqrtf(pe); ssh = ps + bsp[0]; }
  }
  __syncthreads();
  if (t == 0) {
    const float eps = 1e-8f;
    float y[8];
    float m = -1e30f;
    #pragma unroll
    for (int hh = 0; hh < 8; ++hh) {
      float cs = sdot[hh] / ((sne + eps) * (snx[hh] + eps));
      y[hh] = ssh * cs;
      m = fmaxf(m, y[hh]);
    }
    float sum = 0.f;
    #pragma unroll
    for (int hh = 0; hh < 8; ++hh) sum += expf(y[hh] - m);
    float lse = logf(sum);
    float el = 0.f;
    #pragma unroll
    for (int hh = 0; hh < 8; ++hh) {
      float lp = y[hh] - m - lse;
      el += expf(lp) * lp;
    }
    EL[tn] = el;
  }
}

// ---------------------------------------------------------------------------
extern "C" void kernel_launch(void* const* d_in, const int* in_sizes, int n_in,
                              void* d_out, int out_size, void* d_ws, size_t ws_size,
                              hipStream_t stream) {
  (void)in_sizes; (void)n_in; (void)out_size; (void)ws_size;
  const int*   obs    = (const int*)d_in[0];
  const int*   P      = (const int*)d_in[1];
  const float* embed1 = (const float*)d_in[2];
  const float* Wih    = (const float*)d_in[3];
  // d_in[4] = Whh: provably unused (h0 = 0 and only Hs[0] is consumed)
  const float* bih    = (const float*)d_in[5];
  const float* bhh    = (const float*)d_in[6];
  const float* We2    = (const float*)d_in[7];
  const float* be2    = (const float*)d_in[8];
  const float* Ws     = (const float*)d_in[9];
  const float* bs     = (const float*)d_in[10];
  const float* Wc     = (const float*)d_in[11];
  const float* bc     = (const float*)d_in[12];
  const float* Wm1    = (const float*)d_in[13];
  const float* bm1    = (const float*)d_in[14];
  const float* Wm2    = (const float*)d_in[15];
  const float* bm2    = (const float*)d_in[16];
  const float* eo     = (const float*)d_in[17];
  float* out = (float*)d_out;
  char*  ws  = (char*)d_ws;

  float* emb    = (float*)(ws + B_EMB);
  float* h1     = (float*)(ws + B_H1);
  float* xsp    = (float*)(ws + B_XS);
  float* hbuf   = (float*)(ws + B_HBUF);
  float* part   = (float*)(ws + B_PART);
  float* logits = (float*)(ws + B_LOG);
  int*   Ibuf   = (int*)(ws + B_IBUF);
  int*   Iup    = (int*)(ws + B_IUP);
  int*   push   = (int*)(ws + B_PUSH);
  int*   cntp   = (int*)(ws + B_CNT);
  int*   listp  = (int*)(ws + B_LISTP);
  int*   cnttl  = (int*)(ws + B_CNTTL);
  int*   listtl = (int*)(ws + B_LISTTL);
  float* we2t   = (float*)(ws + B_WE2T);
  float* wm1t   = (float*)(ws + B_WM1T);
  float* xstl   = (float*)(ws + B_XSTL);
  float* hbig   = (float*)(ws + B_HBIG);
  float* parttl = (float*)(ws + B_PARTTL);
  float* wm2t   = (float*)(ws + B_WM2T);
  float* wpm    = (float*)(ws + B_WPM);

  dim3 thr(256);
  init_kernel<<<dim3(516), thr, 0, stream>>>(out, logits, cntp, cnttl);
  emb_kernel<<<dim3(256), thr, 0, stream>>>(obs, embed1, emb);
  h1_kernel<<<dim3(256), thr, 0, stream>>>(emb, Wih, bih, bhh, h1);
  trans_kernel<<<dim3(16, 4), thr, 0, stream>>>(We2, we2t, CE, CHID);       // We2T
  x0_kernel<<<dim3(4, 64), thr, 0, stream>>>(h1, we2t, be2, out + O_X);
  trans_kernel<<<dim3(128, 16), thr, 0, stream>>>(Wm1, wm1t, CHID, CA * CE); // Wm1T (overwrites We2T)
  wpm_kernel<<<dim3(256, 4), thr, 0, stream>>>(wm1t, eo, wpm);
  trans_kernel<<<dim3(16, 4), thr, 0, stream>>>(Wm2, wm2t, CE, CHID);       // Wm2T (after wpm)
  tllists_kernel<<<dim3(8), thr, 0, stream>>>(P, cnttl, listtl);
  xstl_kernel<<<dim3(4096), thr, 0, stream>>>(emb, xstl);                   // overwrites Wm1T region
  // time-loop model (factorized, f32): layer1 -> layer2 partials -> loss
  l1_kernel<<<dim3(32, 8, 4), thr, 0, stream>>>(wpm, xstl, bm1, cnttl, listtl, 256, hbig);
  l2big_kernel<<<dim3(4, 64), thr, 0, stream>>>(hbig, wm2t, parttl);
  ml_kernel<<<dim3(2048), thr, 0, stream>>>(parttl, bm2, emb, out + O_ML);
  // planning loop: fin(0) decides step 0; then [l1, l2, fin(s+1)] x 32
  fin_kernel<<<dim3(64), thr, 0, stream>>>(0, P, Ws, bs, Wc, bc, bm2, part,
      out + O_X, out + O_SL, out + O_VAL, out + O_PA, logits, Ibuf, Iup, push,
      xsp, cntp, listp);
  for (int s = 0; s < CS; ++s) {
    l1_kernel<<<dim3(32, 8, 2), thr, 0, stream>>>(wpm, xsp, bm1, cntp, listp, 64, hbuf);
    pl2_kernel<<<dim3(16, 4), thr, 0, stream>>>(hbuf, wm2t, part, cntp);
    fin_kernel<<<dim3(64), thr, 0, stream>>>(s + 1, P, Ws, bs, Wc, bc, bm2, part,
        out + O_X, out + O_SL, out + O_VAL, out + O_PA, logits, Ibuf, Iup, push,
        xsp, cntp, listp);
  }
  el_kernel<<<dim3(2048), thr, 0, stream>>>(emb, out + O_X, Ws, bs, out + O_EL);
}